// Round 7
// baseline (42018.088 us; speedup 1.0000x reference)
//
#include <hip/hip_runtime.h>
#include <cstddef>

#define QD 16   // ctx queue depth

__device__ __forceinline__ float sigm(float x) { return 1.f / (1.f + __expf(-x)); }
__device__ __forceinline__ float tanh_(float x) { return 1.f - 2.f / (__expf(2.f * x) + 1.f); }

#define AGLD(p)    __hip_atomic_load((p),  __ATOMIC_RELAXED, __HIP_MEMORY_SCOPE_AGENT)
#define AGST(p, v) __hip_atomic_store((p), (v), __ATOMIC_RELAXED, __HIP_MEMORY_SCOPE_AGENT)

#define FMA4(acc, wv, xv) do { \
    (acc) = fmaf((wv).x, (xv).x, (acc)); (acc) = fmaf((wv).y, (xv).y, (acc)); \
    (acc) = fmaf((wv).z, (xv).z, (acc)); (acc) = fmaf((wv).w, (xv).w, (acc)); } while (0)

// 16-wide fp32 dot block: accumulates into a0..a3 (declared by caller)
#define DOT16(wp, hp, kk) do { \
    float4 w0_ = *(const float4*)((wp) + (kk));      float4 x0_ = *(const float4*)((hp) + (kk)); \
    float4 w1_ = *(const float4*)((wp) + (kk) + 4);  float4 x1_ = *(const float4*)((hp) + (kk) + 4); \
    float4 w2_ = *(const float4*)((wp) + (kk) + 8);  float4 x2_ = *(const float4*)((hp) + (kk) + 8); \
    float4 w3_ = *(const float4*)((wp) + (kk) + 12); float4 x3_ = *(const float4*)((hp) + (kk) + 12); \
    FMA4(a0, w0_, x0_); FMA4(a1, w1_, x1_); FMA4(a2, w2_, x2_); FMA4(a3, w3_, x3_); } while (0)

// ---------------- K1: embed = relu(inputs @ W_e^T + b_e), layout [s][b][e] ----------------
__global__ __launch_bounds__(256) void k_embed(
    const float* __restrict__ inp, const float* __restrict__ We,
    const float* __restrict__ be, float* __restrict__ emb)
{
  __shared__ float sA[32 * 68];
  __shared__ float sW[32 * 132];
  const int tid = threadIdx.x;
  const int b  = blockIdx.x >> 4;
  const int s0 = (blockIdx.x & 15) << 6;
  float acc[4][8];
#pragma unroll
  for (int i = 0; i < 4; ++i)
#pragma unroll
    for (int j = 0; j < 8; ++j) acc[i][j] = 0.f;
  const int m4 = (tid & 15) << 2;
  const int e8 = (tid >> 4) << 3;
  const float* Ab = inp + ((size_t)(b << 10) + s0) * 1024;
  const int ms = tid >> 2, kq = tid & 3;
  const int es = tid >> 1, kq2 = tid & 1;
  for (int k0 = 0; k0 < 1024; k0 += 32) {
    __syncthreads();
    {
      const float* src = Ab + (size_t)ms * 1024 + k0 + (kq << 3);
      float4 v0 = *(const float4*)(src);
      float4 v1 = *(const float4*)(src + 4);
      int kb = kq << 3;
      sA[(kb+0)*68+ms] = v0.x; sA[(kb+1)*68+ms] = v0.y;
      sA[(kb+2)*68+ms] = v0.z; sA[(kb+3)*68+ms] = v0.w;
      sA[(kb+4)*68+ms] = v1.x; sA[(kb+5)*68+ms] = v1.y;
      sA[(kb+6)*68+ms] = v1.z; sA[(kb+7)*68+ms] = v1.w;
    }
    {
      const float* src = We + (size_t)es * 1024 + k0 + (kq2 << 4);
#pragma unroll
      for (int q = 0; q < 4; ++q) {
        float4 v = *(const float4*)(src + (q << 2));
        int kb = (kq2 << 4) + (q << 2);
        sW[(kb+0)*132+es] = v.x; sW[(kb+1)*132+es] = v.y;
        sW[(kb+2)*132+es] = v.z; sW[(kb+3)*132+es] = v.w;
      }
    }
    __syncthreads();
#pragma unroll 4
    for (int kk = 0; kk < 32; ++kk) {
      float4 a4 = *(const float4*)&sA[kk*68 + m4];
      float4 b0 = *(const float4*)&sW[kk*132 + e8];
      float4 b1 = *(const float4*)&sW[kk*132 + e8 + 4];
      float av[4] = {a4.x, a4.y, a4.z, a4.w};
      float bv[8] = {b0.x, b0.y, b0.z, b0.w, b1.x, b1.y, b1.z, b1.w};
#pragma unroll
      for (int i = 0; i < 4; ++i)
#pragma unroll
        for (int j = 0; j < 8; ++j) acc[i][j] = fmaf(av[i], bv[j], acc[i][j]);
    }
  }
#pragma unroll
  for (int i = 0; i < 4; ++i) {
    int s = s0 + m4 + i;
#pragma unroll
    for (int j = 0; j < 8; ++j) {
      float v = acc[i][j] + be[e8 + j];
      emb[((size_t)(s << 5) + b) * 128 + e8 + j] = v > 0.f ? v : 0.f;
    }
  }
}

// ---------------- K2: a = relu(embed @ Wa1^T + ba1) @ Wa2^T + ba2 ----------------
__global__ __launch_bounds__(256) void k_attn(
    const float* __restrict__ emb, const float* __restrict__ Wa1,
    const float* __restrict__ ba1, const float* __restrict__ Wa2,
    const float* __restrict__ ba2, float* __restrict__ aw)
{
  __shared__ float sE[2 * 128];
  __shared__ float sH[2 * 128];
  const int tid = threadIdx.x;
  const int rs0 = blockIdx.x * 2;
  sE[tid] = emb[(size_t)rs0 * 128 + tid];
  __syncthreads();
  const int half = tid >> 7, j = tid & 127;
  const float* w = Wa1 + j * 128;
  const float* e = sE + half * 128;
  float a0 = 0.f, a1 = 0.f, a2 = 0.f, a3 = 0.f;
  for (int k = 0; k < 128; k += 16) DOT16(w, e, k);
  float h = (a0 + a1) + (a2 + a3) + ba1[j];
  sH[half * 128 + j] = h > 0.f ? h : 0.f;
  __syncthreads();
  if (tid < 6) {
    int hh = tid / 3, l = tid % 3;
    const float* w2 = Wa2 + l * 128;
    const float* hv = sH + hh * 128;
    float s = 0.f;
    for (int k = 0; k < 128; ++k) s = fmaf(w2[k], hv[k], s);
    aw[(size_t)(rs0 + hh) * 3 + l] = s + ba2[l];
  }
}

// ---------------- K2b: softmax over time per (b, l), in-place ----------------
__global__ __launch_bounds__(256) void k_softmax(float* __restrict__ aw)
{
  __shared__ float red[256];
  const int b = blockIdx.x / 3, l = blockIdx.x % 3;
  const int tid = threadIdx.x;
  float v[4];
#pragma unroll
  for (int i = 0; i < 4; ++i) {
    int s = tid + i * 256;
    v[i] = aw[(size_t)(s * 32 + b) * 3 + l];
  }
  float mx = fmaxf(fmaxf(v[0], v[1]), fmaxf(v[2], v[3]));
  red[tid] = mx;
  __syncthreads();
  for (int off = 128; off > 0; off >>= 1) {
    if (tid < off) red[tid] = fmaxf(red[tid], red[tid + off]);
    __syncthreads();
  }
  mx = red[0];
  __syncthreads();
  float sm = 0.f;
#pragma unroll
  for (int i = 0; i < 4; ++i) sm += __expf(v[i] - mx);
  red[tid] = sm;
  __syncthreads();
  for (int off = 128; off > 0; off >>= 1) {
    if (tid < off) red[tid] += red[tid + off];
    __syncthreads();
  }
  float inv = 1.f / red[0];
#pragma unroll
  for (int i = 0; i < 4; ++i) {
    int s = tid + i * 256;
    aw[(size_t)(s * 32 + b) * 3 + l] = __expf(v[i] - mx) * inv;
  }
}

// ---------------- K_prep: repack Wih_d (516-stride) + pre-summed biases ----------------
__global__ __launch_bounds__(256) void k_prep(
    const float* __restrict__ Wih_d,
    const float* __restrict__ bih_e, const float* __restrict__ bhh_e,
    const float* __restrict__ bih_d, const float* __restrict__ bhh_d,
    float* __restrict__ wdpack, float* __restrict__ bsum_e, float* __restrict__ bsum_d)
{
  const int row = blockIdx.x;
  const int tid = threadIdx.x;
  for (int q = tid; q < 516; q += 256) {
    float v = 0.f;
    if (q < 512)       v = Wih_d[(size_t)row * 513 + 1 + q];
    else if (q == 512) v = Wih_d[(size_t)row * 513];
    wdpack[(size_t)row * 516 + q] = v;
  }
  if (tid == 0) {
    bsum_e[row] = bih_e[row] + bhh_e[row];
    bsum_d[row] = bih_d[row] + bhh_d[row];
  }
}

// ---------------- K_init: initial states (slot 1) + barrier zero ----------------
__global__ __launch_bounds__(256) void k_init(
    const float* __restrict__ eh0, const float* __restrict__ dh0,
    float* __restrict__ heb, float* __restrict__ hdb, unsigned* __restrict__ bar)
{
  const int i = blockIdx.x * 256 + threadIdx.x;   // 32768 threads
  if (i < 16384) {
    int k = i & 511;
    heb[16384 + i] = eh0[k];
    hdb[16384 + i] = dh0[k];
  }
  if (i < 2048) bar[i] = 0u;
}

// ---------------- 8-wg barrier (per role, per batch-group), validated R6 mechanism ----------------
__device__ __forceinline__ void grpbar(unsigned* cnt, unsigned* flag, unsigned gen)
{
  __builtin_amdgcn_s_waitcnt(0);
  __syncthreads();
  if (threadIdx.x == 0) {
    asm volatile("" ::: "memory");
    unsigned old = __hip_atomic_fetch_add(cnt, 1u, __ATOMIC_RELAXED, __HIP_MEMORY_SCOPE_AGENT);
    if (old == (gen << 3) - 1u)
      AGST(flag, gen);
    while (AGLD(flag) < gen)
      __builtin_amdgcn_s_sleep(1);
    asm volatile("" ::: "memory");
  }
  __syncthreads();
}

// ---------------- K_persist: concurrent enc & dec pipelines ----------------
// 256 wgs: role = blockIdx>>7 (0=enc, 1=dec), g = (blockIdx>>3)&15 (batch-pair), s = blockIdx&7
// (64-dim slice; s == blockIdx%8 pins slice weights to one XCD's L2).
// Enc: 1 barrier/step (h_e slices); publishes ctx into a QD-deep ring, signals ready[g].
// Dec: 1 barrier/step (h_d slices); consumes ctx (ready-gated), computes p(t-1) locally
// (replicated out-MLP from staged h_d), signals done[g] for enc back-pressure.
__global__ __launch_bounds__(256) void k_persist(
    const float* __restrict__ emb, const float* __restrict__ aw,
    const int* __restrict__ lens,
    const float* __restrict__ Wih_e, const float* __restrict__ Whh_e,
    const float* __restrict__ Whh_d, const float* __restrict__ wdpack,
    const float* __restrict__ bsum_e, const float* __restrict__ bsum_d,
    const float* __restrict__ ec0, const float* __restrict__ dc0,
    const float* __restrict__ Wo1, const float* __restrict__ bo1,
    const float* __restrict__ Wo2, const float* __restrict__ maskp,
    float* __restrict__ heb, float* __restrict__ hdb,
    float* __restrict__ ctxq, float* __restrict__ out,
    unsigned* __restrict__ bar)
{
  __shared__ __align__(16) float sH[1024];    // staged h (both batches)
  __shared__ __align__(16) float sC[1024];    // dec: staged ctx
  __shared__ __align__(16) float sEmb[256];   // enc: embed[t] both batches
  __shared__ float sG[512];                   // gates, 2 batches
  __shared__ float sPa[128], sPb[128], sP[2];
  const int tid = threadIdx.x;
  const int role = blockIdx.x >> 7;
  const int g = (blockIdx.x >> 3) & 15;
  const int s = blockIdx.x & 7;
  const int b0 = g << 1, b1 = b0 + 1;
  const int lane = tid & 63, w = tid >> 6;
  const int r8 = lane >> 3, kg = lane & 7;
  unsigned* cnt   = bar + (role * 16 + g) * 32;
  unsigned* flag  = cnt + 16;
  unsigned* ready = bar + 1024 + g * 16;
  unsigned* done  = bar + 1536 + g * 16;

  // per-thread state for cell updates: tid<128 owns (batch = tid>>6, dim = tid&63)
  const int bsel = tid >> 6, dsel = tid & 63;
  float c_s = 0.f, hm1 = 0.f, hm2 = 0.f;
  int len_b = 0;
  if (tid < 128) {
    c_s = (role == 0) ? ec0[(s << 6) + dsel] : dc0[(s << 6) + dsel];
    len_b = lens[b0 + bsel];
  }
  __syncthreads();

  if (role == 0) {
    // ======================= ENCODER PIPELINE =======================
    for (int t = 0; t < 1024; ++t) {
      // stage h_e(t-1) (UC) + emb[t] (cached)
      {
        const float* hep = heb + (size_t)((t + 1) & 1) * 16384;
        sH[tid]       = AGLD(hep + b0 * 512 + tid);
        sH[tid + 256] = AGLD(hep + b0 * 512 + tid + 256);
        sH[tid + 512] = AGLD(hep + b1 * 512 + tid);
        sH[tid + 768] = AGLD(hep + b1 * 512 + tid + 256);
        if (tid < 128) sEmb[tid] = emb[(size_t)(t * 32 + b0) * 128 + tid];
        else           sEmb[tid] = emb[(size_t)(t * 32 + b1) * 128 + (tid - 128)];
      }
      __syncthreads();

      // distribute lane-slices to registers (reused across all 8 passes)
      float4 h0r[16], h1r[16], e0r[4], e1r[4];
      {
        const float4* sH4 = (const float4*)sH;
        const float4* sE4 = (const float4*)sEmb;
#pragma unroll
        for (int kc = 0; kc < 16; ++kc) { h0r[kc] = sH4[kc*8+kg]; h1r[kc] = sH4[128+kc*8+kg]; }
#pragma unroll
        for (int kc = 0; kc < 4; ++kc)  { e0r[kc] = sE4[kc*8+kg]; e1r[kc] = sE4[32+kc*8+kg]; }
      }

      // gates: 256 rows, octet pattern, 2 batches per weight load
      for (int pass = 0; pass < 8; ++pass) {
        const int rho = pass * 32 + w * 8 + r8;
        const int grow = ((rho >> 6) << 9) + (s << 6) + (rho & 63);
        const float4* wr = (const float4*)(Whh_e + (size_t)grow * 512);
        const float4* wx = (const float4*)(Wih_e + (size_t)grow * 128);
        float fa[2] = {0.f, 0.f}, fb[2] = {0.f, 0.f};
#pragma unroll
        for (int kc = 0; kc < 16; ++kc) {
          float4 wv = wr[kc*8+kg];
          FMA4(fa[kc & 1], wv, h0r[kc]);
          FMA4(fb[kc & 1], wv, h1r[kc]);
        }
#pragma unroll
        for (int kc = 0; kc < 4; ++kc) {
          float4 wv = wx[kc*8+kg];
          FMA4(fa[kc & 1], wv, e0r[kc]);
          FMA4(fb[kc & 1], wv, e1r[kc]);
        }
        float pa = fa[0] + fa[1];
        pa += __shfl_down(pa, 4); pa += __shfl_down(pa, 2); pa += __shfl_down(pa, 1);
        float pb = fb[0] + fb[1];
        pb += __shfl_down(pb, 4); pb += __shfl_down(pb, 2); pb += __shfl_down(pb, 1);
        if (kg == 0) {
          float bs = bsum_e[grow];
          sG[rho] = pa + bs;
          sG[256 + rho] = pb + bs;
        }
      }
      // back-pressure on the ctx ring (slot t % QD reused)
      if (t >= QD && tid == 0) {
        while (AGLD(done) < (unsigned)(t - QD + 1)) __builtin_amdgcn_s_sleep(1);
      }
      __syncthreads();

      // cell + publish h_e slice and ctx slice (UC)
      if (tid < 128) {
        const int bb = b0 + bsel;
        float gi = sG[bsel*256 + dsel],      gf = sG[bsel*256 + 64 + dsel];
        float gg = sG[bsel*256 + 128 + dsel], go = sG[bsel*256 + 192 + dsel];
        c_s = sigm(gf) * c_s + sigm(gi) * tanh_(gg);
        float h = sigm(go) * tanh_(c_s);
        AGST(&heb[(size_t)(t & 1) * 16384 + bb * 512 + (s << 6) + dsel], h);
        float hmv = (t < len_b) ? h : 0.f;
        const float* at = aw + (size_t)(t * 32 + bb) * 3;
        float ctx = at[0] * hmv + at[1] * hm1 + at[2] * hm2;
        hm2 = hm1; hm1 = hmv;
        AGST(&ctxq[(size_t)(t & (QD - 1)) * 16384 + bb * 512 + (s << 6) + dsel], ctx);
      }
      grpbar(cnt, flag, (unsigned)(t + 1));
      if (s == 0 && tid == 0) AGST(ready, (unsigned)(t + 1));
    }
    return;
  }

  // ======================= DECODER PIPELINE =======================
  for (int t = 0; t < 1024; ++t) {
    // wait for ctx(t) from encoder
    if (tid == 0) {
      while (AGLD(ready) < (unsigned)(t + 1)) __builtin_amdgcn_s_sleep(1);
    }
    __syncthreads();
    // stage h_d(t-1) and ctx(t) (UC)
    {
      const float* hdp = hdb + (size_t)((t + 1) & 1) * 16384;
      const float* cp  = ctxq + (size_t)(t & (QD - 1)) * 16384;
      sH[tid]       = AGLD(hdp + b0 * 512 + tid);
      sH[tid + 256] = AGLD(hdp + b0 * 512 + tid + 256);
      sH[tid + 512] = AGLD(hdp + b1 * 512 + tid);
      sH[tid + 768] = AGLD(hdp + b1 * 512 + tid + 256);
      sC[tid]       = AGLD(cp + b0 * 512 + tid);
      sC[tid + 256] = AGLD(cp + b0 * 512 + tid + 256);
      sC[tid + 512] = AGLD(cp + b1 * 512 + tid);
      sC[tid + 768] = AGLD(cp + b1 * 512 + tid + 256);
    }
    __syncthreads();

    // distribute h_d lane-slices to registers (reused by out-MLP + gates)
    float4 h0r[16], h1r[16];
    {
      const float4* sH4 = (const float4*)sH;
#pragma unroll
      for (int kc = 0; kc < 16; ++kc) { h0r[kc] = sH4[kc*8+kg]; h1r[kc] = sH4[128+kc*8+kg]; }
    }

    // p(t-1) via replicated out-MLP (from h_d(t-1) in regs)
    if (t > 0) {
      for (int pass = 0; pass < 4; ++pass) {
        const int e = pass * 32 + w * 8 + r8;
        const float4* wo = (const float4*)(Wo1 + (size_t)e * 512);
        float qa[2] = {0.f, 0.f}, qb[2] = {0.f, 0.f};
#pragma unroll
        for (int kc = 0; kc < 16; ++kc) {
          float4 wv = wo[kc*8+kg];
          FMA4(qa[kc & 1], wv, h0r[kc]);
          FMA4(qb[kc & 1], wv, h1r[kc]);
        }
        float sa = qa[0] + qa[1];
        sa += __shfl_down(sa, 4); sa += __shfl_down(sa, 2); sa += __shfl_down(sa, 1);
        float sb = qb[0] + qb[1];
        sb += __shfl_down(sb, 4); sb += __shfl_down(sb, 2); sb += __shfl_down(sb, 1);
        if (kg == 0) {
          float bo = bo1[e], w2 = Wo2[e];
          float ra = sa + bo; sPa[e] = (ra > 0.f ? ra : 0.f) * w2;
          float rb = sb + bo; sPb[e] = (rb > 0.f ? rb : 0.f) * w2;
        }
      }
      __syncthreads();
      if (w == 0) {
        float v = sPa[lane] + sPa[lane + 64];
        v += __shfl_down(v, 32); v += __shfl_down(v, 16); v += __shfl_down(v, 8);
        v += __shfl_down(v, 4);  v += __shfl_down(v, 2);  v += __shfl_down(v, 1);
        if (lane == 0) sP[0] = v;
      } else if (w == 1) {
        float v = sPb[lane] + sPb[lane + 64];
        v += __shfl_down(v, 32); v += __shfl_down(v, 16); v += __shfl_down(v, 8);
        v += __shfl_down(v, 4);  v += __shfl_down(v, 2);  v += __shfl_down(v, 1);
        if (lane == 0) sP[1] = v;
      }
      __syncthreads();
      if (s == 0 && tid == 0) {
        AGST(&out[(size_t)b0 * 1024 + t - 1], sP[0]);
        AGST(&out[(size_t)b1 * 1024 + t - 1], sP[1]);
      }
    } else {
      if (tid < 2) sP[tid] = 0.f;
      __syncthreads();
    }

    // decoder gates
    for (int pass = 0; pass < 8; ++pass) {
      const int rho = pass * 32 + w * 8 + r8;
      const int grow = ((rho >> 6) << 9) + (s << 6) + (rho & 63);
      const float4* wh = (const float4*)(Whh_d + (size_t)grow * 512);
      const float4* wc = (const float4*)(wdpack + (size_t)grow * 516);
      const float4* sC4 = (const float4*)sC;
      float fa[2] = {0.f, 0.f}, fb[2] = {0.f, 0.f};
#pragma unroll
      for (int kc = 0; kc < 16; ++kc) {
        float4 wv = wh[kc*8+kg];
        FMA4(fa[kc & 1], wv, h0r[kc]);
        FMA4(fb[kc & 1], wv, h1r[kc]);
        float4 cv = wc[kc*8+kg];
        float4 x0 = sC4[kc*8+kg];
        float4 x1 = sC4[128 + kc*8+kg];
        FMA4(fa[kc & 1], cv, x0);
        FMA4(fb[kc & 1], cv, x1);
      }
      float pa = fa[0] + fa[1];
      pa += __shfl_down(pa, 4); pa += __shfl_down(pa, 2); pa += __shfl_down(pa, 1);
      float pb = fb[0] + fb[1];
      pb += __shfl_down(pb, 4); pb += __shfl_down(pb, 2); pb += __shfl_down(pb, 1);
      if (kg == 0) {
        float wp = wdpack[(size_t)grow * 516 + 512];
        float bs = bsum_d[grow];
        sG[rho] = pa + sP[0] * wp + bs;
        sG[256 + rho] = pb + sP[1] * wp + bs;
      }
    }
    __syncthreads();

    // cell + publish h_d slice (UC)
    if (tid < 128) {
      const int bb = b0 + bsel;
      float gi = sG[bsel*256 + dsel],      gf = sG[bsel*256 + 64 + dsel];
      float gg = sG[bsel*256 + 128 + dsel], go = sG[bsel*256 + 192 + dsel];
      c_s = sigm(gf) * c_s + sigm(gi) * tanh_(gg);
      float h = sigm(go) * tanh_(c_s);
      AGST(&hdb[(size_t)(t & 1) * 16384 + bb * 512 + (s << 6) + dsel], h);
    }
    grpbar(cnt, flag, (unsigned)(t + 1));
    if (s == 0 && tid == 0) AGST(done, (unsigned)(t + 1));
  }

  // ---- final p(1023) from h_d(1023) (slot 1) ----
  {
    const float* hdp = hdb + 16384;
    sH[tid]       = AGLD(hdp + b0 * 512 + tid);
    sH[tid + 256] = AGLD(hdp + b0 * 512 + tid + 256);
    sH[tid + 512] = AGLD(hdp + b1 * 512 + tid);
    sH[tid + 768] = AGLD(hdp + b1 * 512 + tid + 256);
  }
  __syncthreads();
  {
    float4 h0r[16], h1r[16];
    const float4* sH4 = (const float4*)sH;
#pragma unroll
    for (int kc = 0; kc < 16; ++kc) { h0r[kc] = sH4[kc*8+kg]; h1r[kc] = sH4[128+kc*8+kg]; }
    for (int pass = 0; pass < 4; ++pass) {
      const int e = pass * 32 + w * 8 + r8;
      const float4* wo = (const float4*)(Wo1 + (size_t)e * 512);
      float qa[2] = {0.f, 0.f}, qb[2] = {0.f, 0.f};
#pragma unroll
      for (int kc = 0; kc < 16; ++kc) {
        float4 wv = wo[kc*8+kg];
        FMA4(qa[kc & 1], wv, h0r[kc]);
        FMA4(qb[kc & 1], wv, h1r[kc]);
      }
      float sa = qa[0] + qa[1];
      sa += __shfl_down(sa, 4); sa += __shfl_down(sa, 2); sa += __shfl_down(sa, 1);
      float sb = qb[0] + qb[1];
      sb += __shfl_down(sb, 4); sb += __shfl_down(sb, 2); sb += __shfl_down(sb, 1);
      if (kg == 0) {
        float bo = bo1[e], w2 = Wo2[e];
        float ra = sa + bo; sPa[e] = (ra > 0.f ? ra : 0.f) * w2;
        float rb = sb + bo; sPb[e] = (rb > 0.f ? rb : 0.f) * w2;
      }
    }
    __syncthreads();
    if (w == 0) {
      float v = sPa[lane] + sPa[lane + 64];
      v += __shfl_down(v, 32); v += __shfl_down(v, 16); v += __shfl_down(v, 8);
      v += __shfl_down(v, 4);  v += __shfl_down(v, 2);  v += __shfl_down(v, 1);
      if (lane == 0) sP[0] = v;
    } else if (w == 1) {
      float v = sPb[lane] + sPb[lane + 64];
      v += __shfl_down(v, 32); v += __shfl_down(v, 16); v += __shfl_down(v, 8);
      v += __shfl_down(v, 4);  v += __shfl_down(v, 2);  v += __shfl_down(v, 1);
      if (lane == 0) sP[1] = v;
    }
    __syncthreads();
    if (s == 0 && tid == 0) {
      AGST(&out[(size_t)b0 * 1024 + 1023], sP[0]);
      AGST(&out[(size_t)b1 * 1024 + 1023], sP[1]);
    }
  }
  grpbar(cnt, flag, 1025u);

  // ---- mask own stripe: out[b][s*128 .. s*128+127] for both batches ----
  {
    const int bb = b0 + (tid >> 7);
    const int idx = bb * 1024 + (s << 7) + (tid & 127);
    float v = AGLD(&out[idx]);
    out[idx] = v * maskp[idx];
  }
}

extern "C" void kernel_launch(void* const* d_in, const int* in_sizes, int n_in,
                              void* d_out, int out_size, void* d_ws, size_t ws_size,
                              hipStream_t stream)
{
  const float* inp   = (const float*)d_in[0];
  const float* maskp = (const float*)d_in[1];
  const int*   lens  = (const int*)d_in[2];
  const float* We    = (const float*)d_in[3];
  const float* be    = (const float*)d_in[4];
  const float* Wa1   = (const float*)d_in[5];
  const float* ba1   = (const float*)d_in[6];
  const float* Wa2   = (const float*)d_in[7];
  const float* ba2   = (const float*)d_in[8];
  const float* Wih_e = (const float*)d_in[9];
  const float* Whh_e = (const float*)d_in[10];
  const float* bih_e = (const float*)d_in[11];
  const float* bhh_e = (const float*)d_in[12];
  const float* eh0   = (const float*)d_in[13];
  const float* ec0   = (const float*)d_in[14];
  const float* Wih_d = (const float*)d_in[15];
  const float* Whh_d = (const float*)d_in[16];
  const float* bih_d = (const float*)d_in[17];
  const float* bhh_d = (const float*)d_in[18];
  const float* dh0   = (const float*)d_in[19];
  const float* dc0   = (const float*)d_in[20];
  const float* Wo1   = (const float*)d_in[21];
  const float* bo1   = (const float*)d_in[22];
  const float* Wo2   = (const float*)d_in[23];
  const float* bo2   = (const float*)d_in[24];

  float* ws     = (float*)d_ws;
  float* emb    = ws;                     // 4,194,304
  float* aw     = emb + 4194304;          //    98,304
  float* heb    = aw + 98304;             //    32,768 (2 slots)
  float* hdb    = heb + 32768;            //    32,768 (2 slots)
  float* ctxq   = hdb + 32768;            //   262,144 (QD=16 slots)
  float* wdpack = ctxq + 262144;          // 1,056,768
  float* bsum_e = wdpack + 1056768;       //     2,048
  float* bsum_d = bsum_e + 2048;          //     2,048
  unsigned* bar = (unsigned*)(bsum_d + 2048);  // 2,048
  float* outf = (float*)d_out;

  k_embed<<<512, 256, 0, stream>>>(inp, We, be, emb);
  k_attn<<<16384, 256, 0, stream>>>(emb, Wa1, ba1, Wa2, ba2, aw);
  k_softmax<<<96, 256, 0, stream>>>(aw);
  k_prep<<<2048, 256, 0, stream>>>(Wih_d, bih_e, bhh_e, bih_d, bhh_d,
                                   wdpack, bsum_e, bsum_d);
  k_init<<<128, 256, 0, stream>>>(eh0, dh0, heb, hdb, bar);

  k_persist<<<256, 256, 0, stream>>>(
      emb, aw, lens,
      Wih_e, Whh_e, Whh_d, wdpack, bsum_e, bsum_d,
      ec0, dc0, Wo1, bo1, Wo2, maskp,
      heb, hdb, ctxq, outf, bar);
}